// Round 1
// baseline (137.035 us; speedup 1.0000x reference)
//
#include <hip/hip_runtime.h>

#define BATCH 2048
#define NIN   128
#define NOUT  128

__device__ __forceinline__ float silu_f(float x) {
    // silu(x) = x / (1 + exp(-x));  exp(-x) = exp2(-x*log2(e))
    float e = __builtin_amdgcn_exp2f(x * -1.44269504088896340736f);
    return x * __builtin_amdgcn_rcpf(1.0f + e);
}

// ---------------- transpose x[B][128] -> xT[128][B] ----------------
__global__ __launch_bounds__(1024) void ktranspose(const float* __restrict__ x,
                                                   float* __restrict__ xT) {
    __shared__ float tile[32][33];
    const int i0 = blockIdx.x * 32;   // feature tile
    const int b0 = blockIdx.y * 32;   // batch tile
    const int tx = threadIdx.x, ty = threadIdx.y;
    tile[ty][tx] = x[(b0 + ty) * NIN + (i0 + tx)];
    __syncthreads();
    xT[(i0 + ty) * BATCH + (b0 + tx)] = tile[tx][ty];
}

// ---------------- layer 0: 16384 subnets, h[b][j] = sum_i f_{i,j}(x[b][i]) ----
__global__ __launch_bounds__(256) void klayer0(
    const float* __restrict__ xT,
    const float* __restrict__ w0, const float* __restrict__ bb0,
    const float* __restrict__ w1, const float* __restrict__ bb1,
    const float* __restrict__ w2, const float* __restrict__ bb2,
    const float* __restrict__ s,  const float* __restrict__ r,
    float* __restrict__ hT)
{
    const int j = blockIdx.x;                       // output feature (uniform)
    const int b = blockIdx.y * 256 + threadIdx.x;   // batch element (per lane)

    float acc = 0.0f;

    #pragma unroll 2
    for (int i = 0; i < NIN; ++i) {
        const int n   = i * NOUT + j;               // wave-uniform net index
        const int n5  = n * 5;
        const int n25 = n * 25;

        const float xv = xT[i * BATCH + b];         // coalesced

        // layer 1: 1 -> 5
        float a[5];
        #pragma unroll
        for (int k = 0; k < 5; ++k)
            a[k] = silu_f(fmaf(w0[n5 + k], xv, bb0[n5 + k]));

        // layer 2: 5 -> 5
        float h2[5];
        #pragma unroll
        for (int k = 0; k < 5; ++k) {
            float u = bb1[n5 + k];
            #pragma unroll
            for (int l = 0; l < 5; ++l)
                u = fmaf(w1[n25 + k * 5 + l], a[l], u);
            h2[k] = silu_f(u);
        }

        // layer 3: 5 -> 1
        float y = bb2[n];
        #pragma unroll
        for (int l = 0; l < 5; ++l)
            y = fmaf(w2[n5 + l], h2[l], y);

        // residual-ish combine + accumulate over i
        acc = fmaf(y, s[n], fmaf(xv, r[n], acc));
    }

    hT[j * BATCH + b] = acc;                        // coalesced
}

// ---------------- layer 1: 128 subnets -> out[b] ----------------
__global__ __launch_bounds__(64) void klayer1(
    const float* __restrict__ hT,
    const float* __restrict__ w0, const float* __restrict__ bb0,
    const float* __restrict__ w1, const float* __restrict__ bb1,
    const float* __restrict__ w2, const float* __restrict__ bb2,
    const float* __restrict__ s,  const float* __restrict__ r,
    float* __restrict__ out)
{
    const int b    = blockIdx.x;
    const int lane = threadIdx.x;

    float acc = 0.0f;

    #pragma unroll
    for (int ii = 0; ii < 2; ++ii) {
        const int i   = lane + ii * 64;             // net index (per lane)
        const int i5  = i * 5;
        const int i25 = i * 25;

        const float xv = hT[i * BATCH + b];

        float a[5];
        #pragma unroll
        for (int k = 0; k < 5; ++k)
            a[k] = silu_f(fmaf(w0[i5 + k], xv, bb0[i5 + k]));

        float h2[5];
        #pragma unroll
        for (int k = 0; k < 5; ++k) {
            float u = bb1[i5 + k];
            #pragma unroll
            for (int l = 0; l < 5; ++l)
                u = fmaf(w1[i25 + k * 5 + l], a[l], u);
            h2[k] = silu_f(u);
        }

        float y = bb2[i];
        #pragma unroll
        for (int l = 0; l < 5; ++l)
            y = fmaf(w2[i5 + l], h2[l], y);

        acc = fmaf(y, s[i], fmaf(xv, r[i], acc));
    }

    // butterfly reduce across the 64-lane wave
    #pragma unroll
    for (int off = 32; off > 0; off >>= 1)
        acc += __shfl_xor(acc, off, 64);

    if (lane == 0) out[b] = acc;
}

extern "C" void kernel_launch(void* const* d_in, const int* in_sizes, int n_in,
                              void* d_out, int out_size, void* d_ws, size_t ws_size,
                              hipStream_t stream) {
    // setup_inputs() dict order:
    // x, w0_0, b0_0, w0_1, b0_1, w0_2, b0_2, s0, r0,
    //    w1_0, b1_0, w1_1, b1_1, w1_2, b1_2, s1, r1
    const float* x    = (const float*)d_in[0];
    const float* w0_0 = (const float*)d_in[1];
    const float* b0_0 = (const float*)d_in[2];
    const float* w0_1 = (const float*)d_in[3];
    const float* b0_1 = (const float*)d_in[4];
    const float* w0_2 = (const float*)d_in[5];
    const float* b0_2 = (const float*)d_in[6];
    const float* s0   = (const float*)d_in[7];
    const float* r0   = (const float*)d_in[8];
    const float* w1_0 = (const float*)d_in[9];
    const float* b1_0 = (const float*)d_in[10];
    const float* w1_1 = (const float*)d_in[11];
    const float* b1_1 = (const float*)d_in[12];
    const float* w1_2 = (const float*)d_in[13];
    const float* b1_2 = (const float*)d_in[14];
    const float* s1   = (const float*)d_in[15];
    const float* r1   = (const float*)d_in[16];

    float* out = (float*)d_out;
    float* xT  = (float*)d_ws;                 // [128][2048] = 1 MB
    float* hT  = xT + (size_t)NIN * BATCH;     // [128][2048] = 1 MB

    ktranspose<<<dim3(NIN / 32, BATCH / 32), dim3(32, 32), 0, stream>>>(x, xT);

    klayer0<<<dim3(NOUT, BATCH / 256), 256, 0, stream>>>(
        xT, w0_0, b0_0, w0_1, b0_1, w0_2, b0_2, s0, r0, hT);

    klayer1<<<BATCH, 64, 0, stream>>>(
        hT, w1_0, b1_0, w1_1, b1_1, w1_2, b1_2, s1, r1, out);
}

// Round 2
// 103.404 us; speedup vs baseline: 1.3252x; 1.3252x over previous
//
#include <hip/hip_runtime.h>

#define BATCH  2048
#define NIN    128
#define NOUT   128
#define NCHUNK 4
#define ILEN   (NIN / NCHUNK)   // 32 i's per chunk

typedef float v2f __attribute__((ext_vector_type(2)));

__device__ __forceinline__ v2f splat(float s) { v2f v; v.x = s; v.y = s; return v; }

__device__ __forceinline__ float silu_f(float x) {
    float e = __builtin_amdgcn_exp2f(x * -1.44269504088896340736f);
    return x * __builtin_amdgcn_rcpf(1.0f + e);
}

__device__ __forceinline__ v2f silu2(v2f x) {
    v2f t = x * -1.44269504088896340736f;
    v2f e, rc;
    e.x = __builtin_amdgcn_exp2f(t.x);
    e.y = __builtin_amdgcn_exp2f(t.y);
    v2f d = e + 1.0f;
    rc.x = __builtin_amdgcn_rcpf(d.x);
    rc.y = __builtin_amdgcn_rcpf(d.y);
    return x * rc;
}

// ---------------- transpose x[B][128] -> xT[128][B] ----------------
__global__ __launch_bounds__(1024) void ktranspose(const float* __restrict__ x,
                                                   float* __restrict__ xT) {
    __shared__ float tile[32][33];
    const int i0 = blockIdx.x * 32;   // feature tile
    const int b0 = blockIdx.y * 32;   // batch tile
    const int tx = threadIdx.x, ty = threadIdx.y;
    tile[ty][tx] = x[(b0 + ty) * NIN + (i0 + tx)];
    __syncthreads();
    xT[(i0 + ty) * BATCH + (b0 + tx)] = tile[tx][ty];
}

// -------- layer 0: i-chunked, 2 batch elems per lane (packed fp32) --------
__global__ __launch_bounds__(256, 8) void klayer0(
    const float* __restrict__ xT,
    const float* __restrict__ w0, const float* __restrict__ bb0,
    const float* __restrict__ w1, const float* __restrict__ bb1,
    const float* __restrict__ w2, const float* __restrict__ bb2,
    const float* __restrict__ s,  const float* __restrict__ r,
    float* __restrict__ hTs)
{
    const int j  = blockIdx.x;                                // output feature (uniform)
    const int c  = blockIdx.z;                                // i-chunk
    const int b2 = (blockIdx.y * 256 + threadIdx.x) * 2;      // batch pair base

    v2f acc = splat(0.0f);
    const int i0 = c * ILEN;

    #pragma unroll 2
    for (int ii = 0; ii < ILEN; ++ii) {
        const int i   = i0 + ii;
        const int n   = i * NOUT + j;                         // wave-uniform net index
        const int n5  = n * 5;
        const int n25 = n * 25;

        const v2f xv = *(const v2f*)(xT + (size_t)i * BATCH + b2);  // coalesced 8B

        // layer 1: 1 -> 5
        v2f a[5];
        #pragma unroll
        for (int k = 0; k < 5; ++k)
            a[k] = silu2(w0[n5 + k] * xv + splat(bb0[n5 + k]));

        // layer 2: 5 -> 5
        v2f h2[5];
        #pragma unroll
        for (int k = 0; k < 5; ++k) {
            v2f u = splat(bb1[n5 + k]);
            #pragma unroll
            for (int l = 0; l < 5; ++l)
                u = w1[n25 + k * 5 + l] * a[l] + u;
            h2[k] = silu2(u);
        }

        // layer 3: 5 -> 1
        v2f y = splat(bb2[n]);
        #pragma unroll
        for (int l = 0; l < 5; ++l)
            y = w2[n5 + l] * h2[l] + y;

        // combine + accumulate over i
        acc = y * s[n] + (xv * r[n] + acc);
    }

    *(v2f*)(hTs + ((size_t)c * NOUT + j) * BATCH + b2) = acc;  // coalesced 8B
}

// -------- layer 1: lane = batch, uniform weights, i-chunked + atomicAdd ----
#define IPB 8   // i's per block
__global__ __launch_bounds__(64) void klayer1(
    const float* __restrict__ hTs,
    const float* __restrict__ w0, const float* __restrict__ bb0,
    const float* __restrict__ w1, const float* __restrict__ bb1,
    const float* __restrict__ w2, const float* __restrict__ bb2,
    const float* __restrict__ s,  const float* __restrict__ r,
    float* __restrict__ out)
{
    const int b  = blockIdx.x * 64 + threadIdx.x;   // batch element (per lane)
    const int i0 = blockIdx.y * IPB;                // i-chunk

    float acc = 0.0f;

    #pragma unroll 2
    for (int ii = 0; ii < IPB; ++ii) {
        const int i  = i0 + ii;                     // wave-uniform net index
        const int i5 = i * 5, i25 = i * 25;

        // sum the 4 partial slices (coalesced)
        float xv = hTs[(0 * NOUT + i) * BATCH + b]
                 + hTs[(1 * NOUT + i) * BATCH + b]
                 + hTs[(2 * NOUT + i) * BATCH + b]
                 + hTs[(3 * NOUT + i) * BATCH + b];

        float a[5];
        #pragma unroll
        for (int k = 0; k < 5; ++k)
            a[k] = silu_f(fmaf(w0[i5 + k], xv, bb0[i5 + k]));

        float h2[5];
        #pragma unroll
        for (int k = 0; k < 5; ++k) {
            float u = bb1[i5 + k];
            #pragma unroll
            for (int l = 0; l < 5; ++l)
                u = fmaf(w1[i25 + k * 5 + l], a[l], u);
            h2[k] = silu_f(u);
        }

        float y = bb2[i];
        #pragma unroll
        for (int l = 0; l < 5; ++l)
            y = fmaf(w2[i5 + l], h2[l], y);

        acc = fmaf(y, s[i], fmaf(xv, r[i], acc));
    }

    atomicAdd(&out[b], acc);
}

extern "C" void kernel_launch(void* const* d_in, const int* in_sizes, int n_in,
                              void* d_out, int out_size, void* d_ws, size_t ws_size,
                              hipStream_t stream) {
    const float* x    = (const float*)d_in[0];
    const float* w0_0 = (const float*)d_in[1];
    const float* b0_0 = (const float*)d_in[2];
    const float* w0_1 = (const float*)d_in[3];
    const float* b0_1 = (const float*)d_in[4];
    const float* w0_2 = (const float*)d_in[5];
    const float* b0_2 = (const float*)d_in[6];
    const float* s0   = (const float*)d_in[7];
    const float* r0   = (const float*)d_in[8];
    const float* w1_0 = (const float*)d_in[9];
    const float* b1_0 = (const float*)d_in[10];
    const float* w1_1 = (const float*)d_in[11];
    const float* b1_1 = (const float*)d_in[12];
    const float* w1_2 = (const float*)d_in[13];
    const float* b1_2 = (const float*)d_in[14];
    const float* s1   = (const float*)d_in[15];
    const float* r1   = (const float*)d_in[16];

    float* out = (float*)d_out;
    float* xT  = (float*)d_ws;                        // [128][2048]         = 1 MB
    float* hTs = xT + (size_t)NIN * BATCH;            // [4][128][2048]      = 4 MB

    ktranspose<<<dim3(NIN / 32, BATCH / 32), dim3(32, 32), 0, stream>>>(x, xT);

    klayer0<<<dim3(NOUT, BATCH / 512, NCHUNK), 256, 0, stream>>>(
        xT, w0_0, b0_0, w0_1, b0_1, w0_2, b0_2, s0, r0, hTs);

    hipMemsetAsync(out, 0, (size_t)BATCH * sizeof(float), stream);

    klayer1<<<dim3(BATCH / 64, NIN / IPB), 64, 0, stream>>>(
        hTs, w1_0, b1_0, w1_1, b1_1, w1_2, b1_2, s1, r1, out);
}